// Round 9
// baseline (423.234 us; speedup 1.0000x reference)
//
#include <hip/hip_runtime.h>
#include <math.h>

#define HDIM 512
#define BDIM 32
#define SDIM 4096
#define MDIM (BDIM * SDIM)   // 131072

typedef __attribute__((ext_vector_type(8))) _Float16 f16x8;
typedef __attribute__((ext_vector_type(4))) float f32x4;

// async global->LDS, 16B per lane; LDS dest is wave-uniform base (+lane*16 by HW)
#define GLL(g, l) __builtin_amdgcn_global_load_lds(                     \
    (const __attribute__((address_space(1))) void*)(g),                \
    (__attribute__((address_space(3))) void*)(l), 16, 0, 0)

// ---------------------------------------------------------------------------
// inputs fp32 -> A fp16 (row-major M x 512)
// ---------------------------------------------------------------------------
__global__ __launch_bounds__(256) void convert_a(
    const float* __restrict__ A, ushort* __restrict__ af)
{
    const size_t nvec = (size_t)MDIM * HDIM / 8;
    size_t idx = (size_t)blockIdx.x * blockDim.x + threadIdx.x;
    const size_t stride = (size_t)gridDim.x * blockDim.x;
    for (; idx < nvec; idx += stride) {
        float4 a0 = ((const float4*)A)[2 * idx];
        float4 a1 = ((const float4*)A)[2 * idx + 1];
        float v[8] = {a0.x, a0.y, a0.z, a0.w, a1.x, a1.y, a1.z, a1.w};
        f16x8 o;
        #pragma unroll
        for (int j = 0; j < 8; ++j) o[j] = (_Float16)v[j];
        ((f16x8*)af)[idx] = o;
    }
}

// ---------------------------------------------------------------------------
// W1 = Ww[:, 0:512] fp32 -> W fp16 (512 x 512, row = h)
// ---------------------------------------------------------------------------
__global__ __launch_bounds__(256) void convert_w(
    const float* __restrict__ Ww, ushort* __restrict__ whi)
{
    const int idx = blockIdx.x * 256 + threadIdx.x;   // 0..32767
    if (idx >= HDIM * HDIM / 8) return;
    const int h  = idx >> 6;
    const int kc = (idx & 63) << 3;
    const float* src = &Ww[(size_t)h * (2 * HDIM) + kc];
    float4 a0 = ((const float4*)src)[0];
    float4 a1 = ((const float4*)src)[1];
    float v[8] = {a0.x, a0.y, a0.z, a0.w, a1.x, a1.y, a1.z, a1.w};
    f16x8 hv;
    #pragma unroll
    for (int j = 0; j < 8; ++j) hv[j] = (_Float16)v[j];
    ((f16x8*)whi)[idx] = hv;
}

// ---------------------------------------------------------------------------
// hb[b,h] = W_b[h] + sum_k hidden[b,k] * W_w[h, HDIM + k]
// ---------------------------------------------------------------------------
__global__ __launch_bounds__(256) void hb_kernel(
    const float* __restrict__ hs, const float* __restrict__ Ww,
    const float* __restrict__ Wb, float* __restrict__ hb)
{
    __shared__ float h_s[HDIM];
    const int b = blockIdx.x;
    for (int i = threadIdx.x; i < HDIM; i += 256) h_s[i] = hs[b * HDIM + i];
    __syncthreads();
    for (int h = threadIdx.x; h < HDIM; h += 256) {
        float acc = Wb[h];
        const float* w = &Ww[(size_t)h * (2 * HDIM) + HDIM];
        #pragma unroll 4
        for (int k = 0; k < HDIM; k += 4) {
            float4 wv = *reinterpret_cast<const float4*>(&w[k]);
            acc += h_s[k] * wv.x + h_s[k + 1] * wv.y + h_s[k + 2] * wv.z + h_s[k + 3] * wv.w;
        }
        hb[b * HDIM + h] = acc;
    }
}

// ---------------------------------------------------------------------------
// vsum 2-stage: part[p][h] = sum_{g in p-th 32-chunk} Vw[g,h]
// ---------------------------------------------------------------------------
__global__ __launch_bounds__(256) void vsum_part(
    const float* __restrict__ Vw, float* __restrict__ part)
{
    const int p = blockIdx.x;          // 0..15
    const int h = threadIdx.x;         // 0..255
    float a0 = 0.f, a1 = 0.f;
    for (int g = p * 32; g < p * 32 + 32; ++g) {
        a0 += Vw[(size_t)g * HDIM + h];
        a1 += Vw[(size_t)g * HDIM + h + 256];
    }
    part[p * HDIM + h] = a0;
    part[p * HDIM + h + 256] = a1;
}

__global__ __launch_bounds__(512) void vsum_fin(
    const float* __restrict__ part, const float* __restrict__ Vb,
    float* __restrict__ vs)
{
    const int h = threadIdx.x;         // 0..511
    float a = 0.f;
    #pragma unroll
    for (int p = 0; p < 16; ++p) a += part[p * HDIM + h];
    vs[h] = a;

    __shared__ float red[512];
    red[h] = Vb[h];
    __syncthreads();
    for (int off = 256; off > 0; off >>= 1) {
        if (h < off) red[h] += red[h + off];
        __syncthreads();
    }
    if (h == 0) vs[HDIM] = red[0];
}

// ---------------------------------------------------------------------------
// scores[m] = vbsum + sum_h tanh( sum_k A[m,k]W1[h,k] + hb[b,h] ) * vs[h]
// Single-product fp16 GEMM (A fp16 x W fp16, fp32 MFMA accum).
// Round-8 structure: BM=256, BN=128, 4 waves (2m x 2n), wave tile 128x64,
// BK=64, 2-barrier K-loop, GLL staging + XOR-granule swizzle (conflict-free).
// LDS 48 KB tiles + ~5 KB tables -> 3 blocks/CU.
// ---------------------------------------------------------------------------
__global__ __launch_bounds__(256, 3) void score_mfma(
    const ushort* __restrict__ Af,  const ushort* __restrict__ Whi,
    const float* __restrict__ hbp,  const float* __restrict__ vsp,
    float* __restrict__ scores)
{
    __shared__ ushort As[256 * 64];                    // 32 KB
    __shared__ ushort Whs[128 * 64];                   // 16 KB
    __shared__ float  hb_s[HDIM], vs_s[HDIM + 1];
    __shared__ float  spred[2][128];

    const int t    = threadIdx.x;
    const int wid  = t >> 6;
    const int lane = t & 63;
    const int wm   = wid >> 1;      // 0/1 : m half (128 rows)
    const int wn   = wid & 1;       // 0/1 : n half (64 cols)
    const int l15  = lane & 15;
    const int l4   = lane >> 4;     // 0..3
    const int m0   = blockIdx.x * 256;
    const int b    = m0 >> 12;      // m0 / 4096

    for (int i = t; i < HDIM; i += 256) { hb_s[i] = hbp[b * HDIM + i]; vs_s[i] = vsp[i]; }
    if (t == 0) vs_s[HDIM] = vsp[HDIM];

    float spart[8][4];
    #pragma unroll
    for (int ii = 0; ii < 8; ++ii)
        #pragma unroll
        for (int r = 0; r < 4; ++r) spart[ii][r] = 0.f;

    #pragma unroll 1
    for (int nt = 0; nt < 4; ++nt) {
        const int n0 = nt << 7;
        f32x4 acc[8][4];
        #pragma unroll
        for (int ii = 0; ii < 8; ++ii)
            #pragma unroll
            for (int jj = 0; jj < 4; ++jj) {
                f32x4 z = {0.f, 0.f, 0.f, 0.f};
                acc[ii][jj] = z;
            }

        #pragma unroll 1
        for (int kt = 0; kt < 8; ++kt) {
            __syncthreads();   // previous tile fully consumed (lgkm drained)

            // stage A 256x64 (8 chunks) + W 128x64 (4 chunks)
            #pragma unroll
            for (int q = 0; q < 8; ++q) {
                const int ib  = q * 256 + (wid << 6);   // wave-uniform base
                const int i   = ib + lane;              // 0..2047
                const int row = i >> 3;                 // 0..255
                const int g   = (i & 7) ^ (row & 7);    // swizzled k-granule
                GLL(Af + (size_t)(m0 + row) * HDIM + (size_t)kt * 64 + g * 8,
                    &As[ib * 8]);
            }
            #pragma unroll
            for (int q = 0; q < 4; ++q) {
                const int ib  = q * 256 + (wid << 6);
                const int i   = ib + lane;              // 0..1023
                const int row = i >> 3;                 // 0..127
                const int g   = (i & 7) ^ (row & 7);
                GLL(Whi + (size_t)(n0 + row) * HDIM + (size_t)kt * 64 + g * 8,
                    &Whs[ib * 8]);
            }
            __syncthreads();   // staging complete (vmcnt drained before barrier)

            #pragma unroll
            for (int ks = 0; ks < 2; ++ks) {
                f16x8 wh[4];
                #pragma unroll
                for (int j = 0; j < 4; ++j) {
                    const int rb = (wn << 6) + (j << 4) + l15;
                    const int sb = ((ks << 2) + l4) ^ (rb & 7);
                    wh[j] = *(const f16x8*)&Whs[rb * 64 + sb * 8];
                }
                #pragma unroll
                for (int i4 = 0; i4 < 8; ++i4) {
                    const int ra = (wm << 7) + (i4 << 4) + l15;
                    const int sa = ((ks << 2) + l4) ^ (ra & 7);
                    f16x8 a = *(const f16x8*)&As[ra * 64 + sa * 8];
                    #pragma unroll
                    for (int j = 0; j < 4; ++j)
                        acc[i4][j] = __builtin_amdgcn_mfma_f32_16x16x32_f16(a, wh[j], acc[i4][j], 0, 0, 0);
                }
            }
        }

        // epilogue: tanh + weighted reduce over this n-tile
        #pragma unroll
        for (int j = 0; j < 4; ++j) {
            const int h = n0 + (wn << 6) + (j << 4) + l15;
            const float hbv = hb_s[h];
            const float vsv = vs_s[h];
            #pragma unroll
            for (int ii = 0; ii < 8; ++ii)
                #pragma unroll
                for (int r = 0; r < 4; ++r) {
                    float x = acc[ii][j][r] + hbv;
                    float e = __expf(2.0f * x);
                    float th = 1.0f - __fdividef(2.0f, e + 1.0f);
                    spart[ii][r] = fmaf(th, vsv, spart[ii][r]);
                }
        }
    }

    // reduce over the 16 column-lanes (rows live in (l4, r))
    #pragma unroll
    for (int ii = 0; ii < 8; ++ii)
        #pragma unroll
        for (int r = 0; r < 4; ++r) {
            float v = spart[ii][r];
            v += __shfl_xor(v, 1);
            v += __shfl_xor(v, 2);
            v += __shfl_xor(v, 4);
            v += __shfl_xor(v, 8);
            spart[ii][r] = v;
        }

    __syncthreads();
    if (wn == 1 && l15 == 0) {
        #pragma unroll
        for (int ii = 0; ii < 8; ++ii)
            #pragma unroll
            for (int r = 0; r < 4; ++r)
                spred[wm][(ii << 4) + (l4 << 2) + r] = spart[ii][r];
    }
    __syncthreads();
    if (wn == 0 && l15 == 0) {
        const float vb = vs_s[HDIM];
        #pragma unroll
        for (int ii = 0; ii < 8; ++ii)
            #pragma unroll
            for (int r = 0; r < 4; ++r) {
                const int mloc = (ii << 4) + (l4 << 2) + r;
                scores[m0 + (wm << 7) + mloc] = spart[ii][r] + spred[wm][mloc] + vb;
            }
    }
}

// ---------------------------------------------------------------------------
// per-b softmax over s (S=4096)
// ---------------------------------------------------------------------------
__global__ __launch_bounds__(256) void softmax_kernel(
    const float* __restrict__ scores, float* __restrict__ attn)
{
    const int b = blockIdx.x;
    const float* s = scores + (size_t)b * SDIM;
    __shared__ float red[256];
    const int t = threadIdx.x;

    float mx = -INFINITY;
    for (int i = t; i < SDIM; i += 256) mx = fmaxf(mx, s[i]);
    red[t] = mx; __syncthreads();
    for (int off = 128; off > 0; off >>= 1) {
        if (t < off) red[t] = fmaxf(red[t], red[t + off]);
        __syncthreads();
    }
    mx = red[0]; __syncthreads();

    float sum = 0.f;
    for (int i = t; i < SDIM; i += 256) sum += expf(s[i] - mx);
    red[t] = sum; __syncthreads();
    for (int off = 128; off > 0; off >>= 1) {
        if (t < off) red[t] += red[t + off];
        __syncthreads();
    }
    const float inv = 1.0f / red[0];

    for (int i = t; i < SDIM; i += 256)
        attn[(size_t)b * SDIM + i] = expf(s[i] - mx) * inv;
}

// ---------------------------------------------------------------------------
// res[m,:] = attn[m] * inputs[m,:]
// ---------------------------------------------------------------------------
__global__ __launch_bounds__(256) void res_kernel(
    const float* __restrict__ A, const float* __restrict__ attn, float* __restrict__ out)
{
    const size_t total = (size_t)MDIM * HDIM / 4;
    size_t idx = (size_t)blockIdx.x * blockDim.x + threadIdx.x;
    const size_t stride = (size_t)gridDim.x * blockDim.x;
    for (; idx < total; idx += stride) {
        const size_t row = idx / (HDIM / 4);
        const float a = attn[row];
        float4 v = reinterpret_cast<const float4*>(A)[idx];
        v.x *= a; v.y *= a; v.z *= a; v.w *= a;
        reinterpret_cast<float4*>(out)[idx] = v;
    }
}

// ---------------------------------------------------------------------------
extern "C" void kernel_launch(void* const* d_in, const int* in_sizes, int n_in,
                              void* d_out, int out_size, void* d_ws, size_t ws_size,
                              hipStream_t stream)
{
    const float* inputs = (const float*)d_in[0];
    const float* hidden = (const float*)d_in[1];
    const float* Ww     = (const float*)d_in[2];
    const float* Wb     = (const float*)d_in[3];
    const float* Vw     = (const float*)d_in[4];
    const float* Vb     = (const float*)d_in[5];

    float* out      = (float*)d_out;
    float* attn_out = out + (size_t)MDIM * HDIM;        // (B,S,1)

    // A_f16 lives in the res region of d_out (128 MB of its 268 MB),
    // overwritten by res_kernel at the end. attn tail untouched.
    ushort* Af = (ushort*)d_out;

    ushort* Whi    = (ushort*)d_ws;                        // 512 KB
    float*  scores = (float*)(Whi + (size_t)HDIM * HDIM);  // 512 KB
    float*  hb     = scores + MDIM;                        // 64 KB
    float*  vs     = hb + BDIM * HDIM;                     // ~2 KB
    float*  part   = vs + HDIM + 1;                        // 32 KB

    convert_a<<<4096, 256, 0, stream>>>(inputs, Af);
    convert_w<<<128, 256, 0, stream>>>(Ww, Whi);
    hb_kernel<<<BDIM, 256, 0, stream>>>(hidden, Ww, Wb, hb);
    vsum_part<<<16, 256, 0, stream>>>(Vw, part);
    vsum_fin<<<1, 512, 0, stream>>>(part, Vb, vs);
    score_mfma<<<MDIM / 256, 256, 0, stream>>>(Af, Whi, hb, vs, scores);
    softmax_kernel<<<BDIM, 256, 0, stream>>>(scores, attn_out);
    res_kernel<<<2048, 256, 0, stream>>>(inputs, attn_out, out);
}

// Round 10
// 378.307 us; speedup vs baseline: 1.1188x; 1.1188x over previous
//
#include <hip/hip_runtime.h>
#include <math.h>

#define HDIM 512
#define BDIM 32
#define SDIM 4096
#define MDIM (BDIM * SDIM)   // 131072

typedef __attribute__((ext_vector_type(8))) _Float16 f16x8;
typedef __attribute__((ext_vector_type(4))) float f32x4;

#define BARRIER() do { asm volatile("" ::: "memory"); \
    __builtin_amdgcn_s_barrier(); \
    asm volatile("" ::: "memory"); } while (0)
#define VMCNT0() asm volatile("s_waitcnt vmcnt(0)" ::: "memory")
#define SCHEDBAR() __builtin_amdgcn_sched_barrier(0)
#define SETPRIO(x) __builtin_amdgcn_s_setprio(x)

// async global->LDS, 16B per lane; LDS dest is wave-uniform base (+lane*16 by HW)
#define GLL(g, l) __builtin_amdgcn_global_load_lds(                     \
    (const __attribute__((address_space(1))) void*)(g),                \
    (__attribute__((address_space(3))) void*)(l), 16, 0, 0)

// ---------------------------------------------------------------------------
// inputs fp32 -> A fp16 (row-major M x 512)
// ---------------------------------------------------------------------------
__global__ __launch_bounds__(256) void convert_a(
    const float* __restrict__ A, ushort* __restrict__ af)
{
    const size_t nvec = (size_t)MDIM * HDIM / 8;
    size_t idx = (size_t)blockIdx.x * blockDim.x + threadIdx.x;
    const size_t stride = (size_t)gridDim.x * blockDim.x;
    for (; idx < nvec; idx += stride) {
        float4 a0 = ((const float4*)A)[2 * idx];
        float4 a1 = ((const float4*)A)[2 * idx + 1];
        float v[8] = {a0.x, a0.y, a0.z, a0.w, a1.x, a1.y, a1.z, a1.w};
        f16x8 o;
        #pragma unroll
        for (int j = 0; j < 8; ++j) o[j] = (_Float16)v[j];
        ((f16x8*)af)[idx] = o;
    }
}

// ---------------------------------------------------------------------------
// W1 = Ww[:, 0:512] fp32 -> W fp16 (512 x 512, row = h)
// ---------------------------------------------------------------------------
__global__ __launch_bounds__(256) void convert_w(
    const float* __restrict__ Ww, ushort* __restrict__ whi)
{
    const int idx = blockIdx.x * 256 + threadIdx.x;   // 0..32767
    if (idx >= HDIM * HDIM / 8) return;
    const int h  = idx >> 6;
    const int kc = (idx & 63) << 3;
    const float* src = &Ww[(size_t)h * (2 * HDIM) + kc];
    float4 a0 = ((const float4*)src)[0];
    float4 a1 = ((const float4*)src)[1];
    float v[8] = {a0.x, a0.y, a0.z, a0.w, a1.x, a1.y, a1.z, a1.w};
    f16x8 hv;
    #pragma unroll
    for (int j = 0; j < 8; ++j) hv[j] = (_Float16)v[j];
    ((f16x8*)whi)[idx] = hv;
}

// ---------------------------------------------------------------------------
// hb[b,h] = W_b[h] + sum_k hidden[b,k] * W_w[h, HDIM + k]
// ---------------------------------------------------------------------------
__global__ __launch_bounds__(256) void hb_kernel(
    const float* __restrict__ hs, const float* __restrict__ Ww,
    const float* __restrict__ Wb, float* __restrict__ hb)
{
    __shared__ float h_s[HDIM];
    const int b = blockIdx.x;
    for (int i = threadIdx.x; i < HDIM; i += 256) h_s[i] = hs[b * HDIM + i];
    __syncthreads();
    for (int h = threadIdx.x; h < HDIM; h += 256) {
        float acc = Wb[h];
        const float* w = &Ww[(size_t)h * (2 * HDIM) + HDIM];
        #pragma unroll 4
        for (int k = 0; k < HDIM; k += 4) {
            float4 wv = *reinterpret_cast<const float4*>(&w[k]);
            acc += h_s[k] * wv.x + h_s[k + 1] * wv.y + h_s[k + 2] * wv.z + h_s[k + 3] * wv.w;
        }
        hb[b * HDIM + h] = acc;
    }
}

// ---------------------------------------------------------------------------
// vsum 2-stage: part[p][h] = sum_{g in p-th 32-chunk} Vw[g,h]
// ---------------------------------------------------------------------------
__global__ __launch_bounds__(256) void vsum_part(
    const float* __restrict__ Vw, float* __restrict__ part)
{
    const int p = blockIdx.x;          // 0..15
    const int h = threadIdx.x;         // 0..255
    float a0 = 0.f, a1 = 0.f;
    for (int g = p * 32; g < p * 32 + 32; ++g) {
        a0 += Vw[(size_t)g * HDIM + h];
        a1 += Vw[(size_t)g * HDIM + h + 256];
    }
    part[p * HDIM + h] = a0;
    part[p * HDIM + h + 256] = a1;
}

__global__ __launch_bounds__(512) void vsum_fin(
    const float* __restrict__ part, const float* __restrict__ Vb,
    float* __restrict__ vs)
{
    const int h = threadIdx.x;         // 0..511
    float a = 0.f;
    #pragma unroll
    for (int p = 0; p < 16; ++p) a += part[p * HDIM + h];
    vs[h] = a;

    __shared__ float red[512];
    red[h] = Vb[h];
    __syncthreads();
    for (int off = 256; off > 0; off >>= 1) {
        if (h < off) red[h] += red[h + off];
        __syncthreads();
    }
    if (h == 0) vs[HDIM] = red[0];
}

// ---------------------------------------------------------------------------
// scores[m] = vbsum + sum_h tanh( sum_k A[m,k]W1[h,k] + hb[b,h] ) * vs[h]
// Single-product fp16 GEMM (fp32 MFMA accum), absmax-proven 0.0156.
// v6: 2-phase pipelined double-buffer (T3 minimum recipe):
//   per K-tile: issue next tile's GLL stage FIRST, then ds_read+MFMA of the
//   current slot, then sched_barrier + vmcnt(0) + s_barrier (ONE per K-tile;
//   GLL flight hides under the MFMA block).
// BM=256, BN=256 (nt=2), BK=64, 512 thr = 8 waves (2m x 4n), wave 128x64.
// LDS: A[2]+W[2] = 128 KB -> 1 block/CU, 2 waves/SIMD.
// slot = kt&1, compile-time via #pragma unroll 2.
// ---------------------------------------------------------------------------
__global__ __launch_bounds__(512, 1) void score_mfma(
    const ushort* __restrict__ Af,  const ushort* __restrict__ Whi,
    const float* __restrict__ hbp,  const float* __restrict__ vsp,
    float* __restrict__ scores)
{
    __shared__ ushort AS[2][256 * 64];   // 2 x 32 KB
    __shared__ ushort WS[2][256 * 64];   // 2 x 32 KB
    __shared__ float  hb_s[HDIM], vs_s[HDIM + 1];
    __shared__ float  spred[4][256];

    const int t    = threadIdx.x;
    const int wid  = t >> 6;
    const int lane = t & 63;
    const int wm   = wid >> 2;      // 0/1  : m half (128 rows)
    const int wn   = wid & 3;       // 0..3 : n quarter (64 cols)
    const int l15  = lane & 15;
    const int l4   = lane >> 4;     // 0..3
    const int m0   = blockIdx.x * 256;
    const int b    = m0 >> 12;      // m0 / 4096

    hb_s[t] = hbp[b * HDIM + t];    // t in [0,512)
    vs_s[t] = vsp[t];
    if (t == 0) vs_s[HDIM] = vsp[HDIM];

    // stage one 256x64 fp16 tile (32 KB): 4 chunks of 512 lanes x 16B,
    // linear LDS dest, XOR-granule-swizzled global source
    auto stageA = [&](int slot, int kt) {
        #pragma unroll
        for (int q = 0; q < 4; ++q) {
            const int i   = q * 512 + t;            // 0..2047
            const int row = i >> 3;                 // 0..255
            const int g   = (i & 7) ^ (row & 7);    // swizzled k-granule
            GLL(Af + (size_t)(m0 + row) * HDIM + (size_t)kt * 64 + g * 8,
                &AS[slot][(q * 8 + wid) * 512]);
        }
    };
    auto stageW = [&](int slot, int n0s, int kt) {
        #pragma unroll
        for (int q = 0; q < 4; ++q) {
            const int i   = q * 512 + t;
            const int row = i >> 3;
            const int g   = (i & 7) ^ (row & 7);
            GLL(Whi + (size_t)(n0s + row) * HDIM + (size_t)kt * 64 + g * 8,
                &WS[slot][(q * 8 + wid) * 512]);
        }
    };

    float spart[8][4];
    #pragma unroll
    for (int ii = 0; ii < 8; ++ii)
        #pragma unroll
        for (int r = 0; r < 4; ++r) spart[ii][r] = 0.f;

    // prologue: tile (nt=0, kt=0) -> slot 0
    stageA(0, 0);
    stageW(0, 0, 0);
    VMCNT0();
    BARRIER();

    #pragma unroll 1
    for (int nt = 0; nt < 2; ++nt) {
        const int n0 = nt << 8;
        f32x4 acc[8][4];
        #pragma unroll
        for (int ii = 0; ii < 8; ++ii)
            #pragma unroll
            for (int jj = 0; jj < 4; ++jj) {
                f32x4 z = {0.f, 0.f, 0.f, 0.f};
                acc[ii][jj] = z;
            }

        #pragma unroll 2
        for (int kt = 0; kt < 8; ++kt) {
            const int slot = kt & 1;        // compile-time under unroll 2
            const bool last = (nt == 1) && (kt == 7);

            // --- phase A: issue next tile's stage into the other slot
            if (!last) {
                const int ktn = (kt + 1) & 7;
                const int n0n = (kt == 7) ? 256 : n0;
                stageA(slot ^ 1, ktn);
                stageW(slot ^ 1, n0n, ktn);
            }

            // --- phase B: compute current slot (GLLs fly underneath)
            #pragma unroll
            for (int ks = 0; ks < 2; ++ks) {
                f16x8 wh[4];
                #pragma unroll
                for (int j = 0; j < 4; ++j) {
                    const int rb = (wn << 6) + (j << 4) + l15;
                    const int sb = ((ks << 2) + l4) ^ (rb & 7);
                    wh[j] = *(const f16x8*)&WS[slot][rb * 64 + sb * 8];
                }
                SETPRIO(1);
                #pragma unroll
                for (int i4 = 0; i4 < 8; ++i4) {
                    const int ra = (wm << 7) + (i4 << 4) + l15;
                    const int sa = ((ks << 2) + l4) ^ (ra & 7);
                    f16x8 a = *(const f16x8*)&AS[slot][ra * 64 + sa * 8];
                    #pragma unroll
                    for (int j = 0; j < 4; ++j)
                        acc[i4][j] = __builtin_amdgcn_mfma_f32_16x16x32_f16(a, wh[j], acc[i4][j], 0, 0, 0);
                }
                SETPRIO(0);
            }

            // --- phase C: one drain+barrier per K-tile.
            // sched_barrier pins MFMAs (and their lgkmcnt waits) before the
            // barrier so no in-flight ds_read of this slot crosses it.
            SCHEDBAR();
            VMCNT0();
            BARRIER();
        }

        // epilogue: tanh + weighted reduce for this n-half (regs + tables only)
        #pragma unroll
        for (int j = 0; j < 4; ++j) {
            const int h = n0 + (wn << 6) + (j << 4) + l15;
            const float hbv = hb_s[h];
            const float vsv = vs_s[h];
            #pragma unroll
            for (int ii = 0; ii < 8; ++ii)
                #pragma unroll
                for (int r = 0; r < 4; ++r) {
                    float x = acc[ii][j][r] + hbv;
                    float e = __expf(2.0f * x);
                    float th = 1.0f - __fdividef(2.0f, e + 1.0f);
                    spart[ii][r] = fmaf(th, vsv, spart[ii][r]);
                }
        }
    }

    // reduce over the 16 column-lanes (rows live in (l4, r))
    #pragma unroll
    for (int ii = 0; ii < 8; ++ii)
        #pragma unroll
        for (int r = 0; r < 4; ++r) {
            float v = spart[ii][r];
            v += __shfl_xor(v, 1);
            v += __shfl_xor(v, 2);
            v += __shfl_xor(v, 4);
            v += __shfl_xor(v, 8);
            spart[ii][r] = v;
        }

    __syncthreads();
    if (l15 == 0) {
        #pragma unroll
        for (int ii = 0; ii < 8; ++ii)
            #pragma unroll
            for (int r = 0; r < 4; ++r)
                spred[wn][(wm << 7) + (ii << 4) + (l4 << 2) + r] = spart[ii][r];
    }
    __syncthreads();
    if (wn == 0 && l15 == 0) {
        const float vb = vs_s[HDIM];
        #pragma unroll
        for (int ii = 0; ii < 8; ++ii)
            #pragma unroll
            for (int r = 0; r < 4; ++r) {
                const int ml = (wm << 7) + (ii << 4) + (l4 << 2) + r;
                scores[m0 + ml] = spred[0][ml] + spred[1][ml] + spred[2][ml]
                                + spred[3][ml] + vb;
            }
    }
}

// ---------------------------------------------------------------------------
// per-b softmax over s (S=4096)
// ---------------------------------------------------------------------------
__global__ __launch_bounds__(256) void softmax_kernel(
    const float* __restrict__ scores, float* __restrict__ attn)
{
    const int b = blockIdx.x;
    const float* s = scores + (size_t)b * SDIM;
    __shared__ float red[256];
    const int t = threadIdx.x;

    float mx = -INFINITY;
    for (int i = t; i < SDIM; i += 256) mx = fmaxf(mx, s[i]);
    red[t] = mx; __syncthreads();
    for (int off = 128; off > 0; off >>= 1) {
        if (t < off) red[t] = fmaxf(red[t], red[t + off]);
        __syncthreads();
    }
    mx = red[0]; __syncthreads();

    float sum = 0.f;
    for (int i = t; i < SDIM; i += 256) sum += expf(s[i] - mx);
    red[t] = sum; __syncthreads();
    for (int off = 128; off > 0; off >>= 1) {
        if (t < off) red[t] += red[t + off];
        __syncthreads();
    }
    const float inv = 1.0f / red[0];

    for (int i = t; i < SDIM; i += 256)
        attn[(size_t)b * SDIM + i] = expf(s[i] - mx) * inv;
}

// ---------------------------------------------------------------------------
// res[m,:] = attn[m] * inputs[m,:]
// ---------------------------------------------------------------------------
__global__ __launch_bounds__(256) void res_kernel(
    const float* __restrict__ A, const float* __restrict__ attn, float* __restrict__ out)
{
    const size_t total = (size_t)MDIM * HDIM / 4;
    size_t idx = (size_t)blockIdx.x * blockDim.x + threadIdx.x;
    const size_t stride = (size_t)gridDim.x * blockDim.x;
    for (; idx < total; idx += stride) {
        const size_t row = idx / (HDIM / 4);
        const float a = attn[row];
        float4 v = reinterpret_cast<const float4*>(A)[idx];
        v.x *= a; v.y *= a; v.z *= a; v.w *= a;
        reinterpret_cast<float4*>(out)[idx] = v;
    }
}

// ---------------------------------------------------------------------------
extern "C" void kernel_launch(void* const* d_in, const int* in_sizes, int n_in,
                              void* d_out, int out_size, void* d_ws, size_t ws_size,
                              hipStream_t stream)
{
    const float* inputs = (const float*)d_in[0];
    const float* hidden = (const float*)d_in[1];
    const float* Ww     = (const float*)d_in[2];
    const float* Wb     = (const float*)d_in[3];
    const float* Vw     = (const float*)d_in[4];
    const float* Vb     = (const float*)d_in[5];

    float* out      = (float*)d_out;
    float* attn_out = out + (size_t)MDIM * HDIM;        // (B,S,1)

    // A_f16 lives in the res region of d_out (128 MB of its 268 MB),
    // overwritten by res_kernel at the end. attn tail untouched.
    ushort* Af = (ushort*)d_out;

    ushort* Whi    = (ushort*)d_ws;                        // 512 KB
    float*  scores = (float*)(Whi + (size_t)HDIM * HDIM);  // 512 KB
    float*  hb     = scores + MDIM;                        // 64 KB
    float*  vs     = hb + BDIM * HDIM;                     // ~2 KB
    float*  part   = vs + HDIM + 1;                        // 32 KB

    convert_a<<<4096, 256, 0, stream>>>(inputs, Af);
    convert_w<<<128, 256, 0, stream>>>(Ww, Whi);
    hb_kernel<<<BDIM, 256, 0, stream>>>(hidden, Ww, Wb, hb);
    vsum_part<<<16, 256, 0, stream>>>(Vw, part);
    vsum_fin<<<1, 512, 0, stream>>>(part, Vb, vs);
    score_mfma<<<MDIM / 256, 512, 0, stream>>>(Af, Whi, hb, vs, scores);
    softmax_kernel<<<BDIM, 256, 0, stream>>>(scores, attn_out);
    res_kernel<<<2048, 256, 0, stream>>>(inputs, attn_out, out);
}

// Round 11
// 323.166 us; speedup vs baseline: 1.3096x; 1.1706x over previous
//
#include <hip/hip_runtime.h>
#include <math.h>

#define HDIM 512
#define BDIM 32
#define SDIM 4096
#define MDIM (BDIM * SDIM)   // 131072

typedef __attribute__((ext_vector_type(8))) _Float16 f16x8;
typedef __attribute__((ext_vector_type(4))) float f32x4;

// async global->LDS, 16B per lane; LDS dest is wave-uniform base (+lane*16 by HW)
#define GLL(g, l) __builtin_amdgcn_global_load_lds(                     \
    (const __attribute__((address_space(1))) void*)(g),                \
    (__attribute__((address_space(3))) void*)(l), 16, 0, 0)

// ---------------------------------------------------------------------------
// inputs fp32 -> A fp16 (row-major M x 512)
// ---------------------------------------------------------------------------
__global__ __launch_bounds__(256) void convert_a(
    const float* __restrict__ A, ushort* __restrict__ af)
{
    const size_t nvec = (size_t)MDIM * HDIM / 8;
    size_t idx = (size_t)blockIdx.x * blockDim.x + threadIdx.x;
    const size_t stride = (size_t)gridDim.x * blockDim.x;
    for (; idx < nvec; idx += stride) {
        float4 a0 = ((const float4*)A)[2 * idx];
        float4 a1 = ((const float4*)A)[2 * idx + 1];
        float v[8] = {a0.x, a0.y, a0.z, a0.w, a1.x, a1.y, a1.z, a1.w};
        f16x8 o;
        #pragma unroll
        for (int j = 0; j < 8; ++j) o[j] = (_Float16)v[j];
        ((f16x8*)af)[idx] = o;
    }
}

// ---------------------------------------------------------------------------
// W1 = Ww[:, 0:512] fp32 -> W fp16 (512 x 512, row = h)
// ---------------------------------------------------------------------------
__global__ __launch_bounds__(256) void convert_w(
    const float* __restrict__ Ww, ushort* __restrict__ whi)
{
    const int idx = blockIdx.x * 256 + threadIdx.x;   // 0..32767
    if (idx >= HDIM * HDIM / 8) return;
    const int h  = idx >> 6;
    const int kc = (idx & 63) << 3;
    const float* src = &Ww[(size_t)h * (2 * HDIM) + kc];
    float4 a0 = ((const float4*)src)[0];
    float4 a1 = ((const float4*)src)[1];
    float v[8] = {a0.x, a0.y, a0.z, a0.w, a1.x, a1.y, a1.z, a1.w};
    f16x8 hv;
    #pragma unroll
    for (int j = 0; j < 8; ++j) hv[j] = (_Float16)v[j];
    ((f16x8*)whi)[idx] = hv;
}

// ---------------------------------------------------------------------------
// hb[b,h] = W_b[h] + sum_k hidden[b,k] * W_w[h, HDIM + k]
// ---------------------------------------------------------------------------
__global__ __launch_bounds__(256) void hb_kernel(
    const float* __restrict__ hs, const float* __restrict__ Ww,
    const float* __restrict__ Wb, float* __restrict__ hb)
{
    __shared__ float h_s[HDIM];
    const int b = blockIdx.x;
    for (int i = threadIdx.x; i < HDIM; i += 256) h_s[i] = hs[b * HDIM + i];
    __syncthreads();
    for (int h = threadIdx.x; h < HDIM; h += 256) {
        float acc = Wb[h];
        const float* w = &Ww[(size_t)h * (2 * HDIM) + HDIM];
        #pragma unroll 4
        for (int k = 0; k < HDIM; k += 4) {
            float4 wv = *reinterpret_cast<const float4*>(&w[k]);
            acc += h_s[k] * wv.x + h_s[k + 1] * wv.y + h_s[k + 2] * wv.z + h_s[k + 3] * wv.w;
        }
        hb[b * HDIM + h] = acc;
    }
}

// ---------------------------------------------------------------------------
// vsum 2-stage: part[p][h] = sum_{g in p-th 32-chunk} Vw[g,h]
// ---------------------------------------------------------------------------
__global__ __launch_bounds__(256) void vsum_part(
    const float* __restrict__ Vw, float* __restrict__ part)
{
    const int p = blockIdx.x;          // 0..15
    const int h = threadIdx.x;         // 0..255
    float a0 = 0.f, a1 = 0.f;
    for (int g = p * 32; g < p * 32 + 32; ++g) {
        a0 += Vw[(size_t)g * HDIM + h];
        a1 += Vw[(size_t)g * HDIM + h + 256];
    }
    part[p * HDIM + h] = a0;
    part[p * HDIM + h + 256] = a1;
}

__global__ __launch_bounds__(512) void vsum_fin(
    const float* __restrict__ part, const float* __restrict__ Vb,
    float* __restrict__ vs)
{
    const int h = threadIdx.x;         // 0..511
    float a = 0.f;
    #pragma unroll
    for (int p = 0; p < 16; ++p) a += part[p * HDIM + h];
    vs[h] = a;

    __shared__ float red[512];
    red[h] = Vb[h];
    __syncthreads();
    for (int off = 256; off > 0; off >>= 1) {
        if (h < off) red[h] += red[h + off];
        __syncthreads();
    }
    if (h == 0) vs[HDIM] = red[0];
}

// ---------------------------------------------------------------------------
// scores[m] = vbsum + sum_h tanh( sum_k A[m,k]W1[h,k] + hb[b,h] ) * vs[h]
// v7: A-IN-REGISTERS, W-SLICE-STREAMING.
//   block = 4 waves x 32 m-rows (BM=128, grid 1024). Each wave holds its
//   32 rows x full K=512 of A fp16 in 128 VGPRs (loaded once, coalesced,
//   never re-staged). Loop over 8 n-slices of W (64 rows x 512 k = 64 KB
//   LDS via GLL, XOR-granule swizzle): per slice 128 MFMA/wave + fused
//   tanh*vs epilogue into per-row spart. No cross-wave reduction needed.
//   Steps/block = 8 (vs 32 before); A fetch = 128 MB exactly; W is
//   L2-resident. LDS 68 KB -> 2 blocks/CU.
// ---------------------------------------------------------------------------
__global__ __launch_bounds__(256, 2) void score_mfma(
    const ushort* __restrict__ Af,  const ushort* __restrict__ Whi,
    const float* __restrict__ hbp,  const float* __restrict__ vsp,
    float* __restrict__ scores)
{
    __shared__ ushort Ws[64 * 512];          // 64 KB: one W n-slice, full K
    __shared__ float  hb_s[HDIM], vs_s[HDIM + 1];

    const int t    = threadIdx.x;
    const int wid  = t >> 6;        // 0..3
    const int lane = t & 63;
    const int l15  = lane & 15;
    const int l4   = lane >> 4;     // 0..3
    const int m0   = blockIdx.x * 128;
    const int b    = m0 >> 12;      // m0 / 4096

    for (int i = t; i < HDIM; i += 256) { hb_s[i] = hbp[b * HDIM + i]; vs_s[i] = vsp[i]; }
    if (t == 0) vs_s[HDIM] = vsp[HDIM];

    // ---- A: 32 rows x K=512 per wave, straight to registers (coalesced:
    // lanes l4=0..3 of a row cover a 64B line; 16 rows per instruction).
    f16x8 a[2][16];
    const ushort* abase = Af + (size_t)(m0 + (wid << 5) + l15) * HDIM + (l4 << 3);
    #pragma unroll
    for (int i = 0; i < 2; ++i)
        #pragma unroll
        for (int ks = 0; ks < 16; ++ks)
            a[i][ks] = *(const f16x8*)(abase + (size_t)(i << 4) * HDIM + ks * 32);

    float spart[2][4];
    #pragma unroll
    for (int i = 0; i < 2; ++i)
        #pragma unroll
        for (int r = 0; r < 4; ++r) spart[i][r] = 0.f;

    #pragma unroll 1
    for (int s = 0; s < 8; ++s) {
        const int n0 = s << 6;

        __syncthreads();   // previous slice fully consumed
        // stage W slice: 64 rows x 1 KB; one GLL covers one row (64 lanes x 16B).
        // LDS linear; global granule pre-swizzled: lds[row][gl] = glob[row][gl ^ (row&7)]
        #pragma unroll
        for (int q = 0; q < 16; ++q) {
            const int row = (q << 2) + wid;              // 0..63
            const int g   = lane ^ (row & 7);            // swizzled 16B granule
            GLL(Whi + (size_t)(n0 + row) * HDIM + g * 8, &Ws[row * HDIM]);
        }
        __syncthreads();   // staging complete (vmcnt drained before barrier)

        f32x4 acc[2][4];
        #pragma unroll
        for (int i = 0; i < 2; ++i)
            #pragma unroll
            for (int j = 0; j < 4; ++j) {
                f32x4 z = {0.f, 0.f, 0.f, 0.f};
                acc[i][j] = z;
            }

        #pragma unroll
        for (int ks = 0; ks < 16; ++ks) {
            f16x8 wh[4];
            #pragma unroll
            for (int j = 0; j < 4; ++j) {
                const int rb = (j << 4) + l15;                   // W row in slice
                const int g  = ((ks << 2) + l4) ^ (rb & 7);      // swizzled granule
                wh[j] = *(const f16x8*)&Ws[rb * HDIM + g * 8];
            }
            #pragma unroll
            for (int i = 0; i < 2; ++i)
                #pragma unroll
                for (int j = 0; j < 4; ++j)
                    acc[i][j] = __builtin_amdgcn_mfma_f32_16x16x32_f16(a[i][ks], wh[j], acc[i][j], 0, 0, 0);
        }

        // fused epilogue for this n-slice: tanh + weighted reduce
        #pragma unroll
        for (int j = 0; j < 4; ++j) {
            const int h   = n0 + (j << 4) + l15;
            const float hbv = hb_s[h];
            const float vsv = vs_s[h];
            #pragma unroll
            for (int i = 0; i < 2; ++i)
                #pragma unroll
                for (int r = 0; r < 4; ++r) {
                    float x  = acc[i][j][r] + hbv;
                    float e  = __expf(2.0f * x);
                    float th = 1.0f - __fdividef(2.0f, e + 1.0f);
                    spart[i][r] = fmaf(th, vsv, spart[i][r]);
                }
        }
    }

    // reduce over the 16 column-lanes; rows live in (l4, r)
    #pragma unroll
    for (int i = 0; i < 2; ++i)
        #pragma unroll
        for (int r = 0; r < 4; ++r) {
            float v = spart[i][r];
            v += __shfl_xor(v, 1);
            v += __shfl_xor(v, 2);
            v += __shfl_xor(v, 4);
            v += __shfl_xor(v, 8);
            spart[i][r] = v;
        }

    if (l15 == 0) {
        const float vb = vs_s[HDIM];
        #pragma unroll
        for (int i = 0; i < 2; ++i)
            #pragma unroll
            for (int r = 0; r < 4; ++r)
                scores[m0 + (wid << 5) + (i << 4) + (l4 << 2) + r] = spart[i][r] + vb;
    }
}

// ---------------------------------------------------------------------------
// per-b softmax over s (S=4096)
// ---------------------------------------------------------------------------
__global__ __launch_bounds__(256) void softmax_kernel(
    const float* __restrict__ scores, float* __restrict__ attn)
{
    const int b = blockIdx.x;
    const float* s = scores + (size_t)b * SDIM;
    __shared__ float red[256];
    const int t = threadIdx.x;

    float mx = -INFINITY;
    for (int i = t; i < SDIM; i += 256) mx = fmaxf(mx, s[i]);
    red[t] = mx; __syncthreads();
    for (int off = 128; off > 0; off >>= 1) {
        if (t < off) red[t] = fmaxf(red[t], red[t + off]);
        __syncthreads();
    }
    mx = red[0]; __syncthreads();

    float sum = 0.f;
    for (int i = t; i < SDIM; i += 256) sum += expf(s[i] - mx);
    red[t] = sum; __syncthreads();
    for (int off = 128; off > 0; off >>= 1) {
        if (t < off) red[t] += red[t + off];
        __syncthreads();
    }
    const float inv = 1.0f / red[0];

    for (int i = t; i < SDIM; i += 256)
        attn[(size_t)b * SDIM + i] = expf(s[i] - mx) * inv;
}

// ---------------------------------------------------------------------------
// res[m,:] = attn[m] * inputs[m,:]
// ---------------------------------------------------------------------------
__global__ __launch_bounds__(256) void res_kernel(
    const float* __restrict__ A, const float* __restrict__ attn, float* __restrict__ out)
{
    const size_t total = (size_t)MDIM * HDIM / 4;
    size_t idx = (size_t)blockIdx.x * blockDim.x + threadIdx.x;
    const size_t stride = (size_t)gridDim.x * blockDim.x;
    for (; idx < total; idx += stride) {
        const size_t row = idx / (HDIM / 4);
        const float a = attn[row];
        float4 v = reinterpret_cast<const float4*>(A)[idx];
        v.x *= a; v.y *= a; v.z *= a; v.w *= a;
        reinterpret_cast<float4*>(out)[idx] = v;
    }
}

// ---------------------------------------------------------------------------
extern "C" void kernel_launch(void* const* d_in, const int* in_sizes, int n_in,
                              void* d_out, int out_size, void* d_ws, size_t ws_size,
                              hipStream_t stream)
{
    const float* inputs = (const float*)d_in[0];
    const float* hidden = (const float*)d_in[1];
    const float* Ww     = (const float*)d_in[2];
    const float* Wb     = (const float*)d_in[3];
    const float* Vw     = (const float*)d_in[4];
    const float* Vb     = (const float*)d_in[5];

    float* out      = (float*)d_out;
    float* attn_out = out + (size_t)MDIM * HDIM;        // (B,S,1)

    // A_f16 lives in the res region of d_out (128 MB of its 268 MB),
    // overwritten by res_kernel at the end. attn tail untouched.
    ushort* Af = (ushort*)d_out;

    ushort* Whi    = (ushort*)d_ws;                        // 512 KB
    float*  scores = (float*)(Whi + (size_t)HDIM * HDIM);  // 512 KB
    float*  hb     = scores + MDIM;                        // 64 KB
    float*  vs     = hb + BDIM * HDIM;                     // ~2 KB
    float*  part   = vs + HDIM + 1;                        // 32 KB

    convert_a<<<4096, 256, 0, stream>>>(inputs, Af);
    convert_w<<<128, 256, 0, stream>>>(Ww, Whi);
    hb_kernel<<<BDIM, 256, 0, stream>>>(hidden, Ww, Wb, hb);
    vsum_part<<<16, 256, 0, stream>>>(Vw, part);
    vsum_fin<<<1, 512, 0, stream>>>(part, Vb, vs);
    score_mfma<<<MDIM / 128, 256, 0, stream>>>(Af, Whi, hb, vs, scores);
    softmax_kernel<<<BDIM, 256, 0, stream>>>(scores, attn_out);
    res_kernel<<<2048, 256, 0, stream>>>(inputs, attn_out, out);
}

// Round 12
// 279.531 us; speedup vs baseline: 1.5141x; 1.1561x over previous
//
#include <hip/hip_runtime.h>
#include <math.h>

#define HDIM 512
#define BDIM 32
#define SDIM 4096
#define MDIM (BDIM * SDIM)   // 131072

typedef __attribute__((ext_vector_type(8))) _Float16 f16x8;
typedef __attribute__((ext_vector_type(4))) float f32x4;

// async global->LDS, 16B per lane; LDS dest is wave-uniform base (+lane*16 by HW)
#define GLL(g, l) __builtin_amdgcn_global_load_lds(                     \
    (const __attribute__((address_space(1))) void*)(g),                \
    (__attribute__((address_space(3))) void*)(l), 16, 0, 0)

// ---------------------------------------------------------------------------
// W1 = Ww[:, 0:512] fp32 -> W fp16 (512 x 512, row = h)
// ---------------------------------------------------------------------------
__global__ __launch_bounds__(256) void convert_w(
    const float* __restrict__ Ww, ushort* __restrict__ whi)
{
    const int idx = blockIdx.x * 256 + threadIdx.x;   // 0..32767
    if (idx >= HDIM * HDIM / 8) return;
    const int h  = idx >> 6;
    const int kc = (idx & 63) << 3;
    const float* src = &Ww[(size_t)h * (2 * HDIM) + kc];
    float4 a0 = ((const float4*)src)[0];
    float4 a1 = ((const float4*)src)[1];
    float v[8] = {a0.x, a0.y, a0.z, a0.w, a1.x, a1.y, a1.z, a1.w};
    f16x8 hv;
    #pragma unroll
    for (int j = 0; j < 8; ++j) hv[j] = (_Float16)v[j];
    ((f16x8*)whi)[idx] = hv;
}

// ---------------------------------------------------------------------------
// hb[b,h] = W_b[h] + sum_k hidden[b,k] * W_w[h, HDIM + k]
// ---------------------------------------------------------------------------
__global__ __launch_bounds__(256) void hb_kernel(
    const float* __restrict__ hs, const float* __restrict__ Ww,
    const float* __restrict__ Wb, float* __restrict__ hb)
{
    __shared__ float h_s[HDIM];
    const int b = blockIdx.x;
    for (int i = threadIdx.x; i < HDIM; i += 256) h_s[i] = hs[b * HDIM + i];
    __syncthreads();
    for (int h = threadIdx.x; h < HDIM; h += 256) {
        float acc = Wb[h];
        const float* w = &Ww[(size_t)h * (2 * HDIM) + HDIM];
        #pragma unroll 4
        for (int k = 0; k < HDIM; k += 4) {
            float4 wv = *reinterpret_cast<const float4*>(&w[k]);
            acc += h_s[k] * wv.x + h_s[k + 1] * wv.y + h_s[k + 2] * wv.z + h_s[k + 3] * wv.w;
        }
        hb[b * HDIM + h] = acc;
    }
}

// ---------------------------------------------------------------------------
// vsum 2-stage: part[p][h] = sum_{g in p-th 32-chunk} Vw[g,h]
// ---------------------------------------------------------------------------
__global__ __launch_bounds__(256) void vsum_part(
    const float* __restrict__ Vw, float* __restrict__ part)
{
    const int p = blockIdx.x;          // 0..15
    const int h = threadIdx.x;         // 0..255
    float a0 = 0.f, a1 = 0.f;
    for (int g = p * 32; g < p * 32 + 32; ++g) {
        a0 += Vw[(size_t)g * HDIM + h];
        a1 += Vw[(size_t)g * HDIM + h + 256];
    }
    part[p * HDIM + h] = a0;
    part[p * HDIM + h + 256] = a1;
}

__global__ __launch_bounds__(512) void vsum_fin(
    const float* __restrict__ part, const float* __restrict__ Vb,
    float* __restrict__ vs)
{
    const int h = threadIdx.x;         // 0..511
    float a = 0.f;
    #pragma unroll
    for (int p = 0; p < 16; ++p) a += part[p * HDIM + h];
    vs[h] = a;

    __shared__ float red[512];
    red[h] = Vb[h];
    __syncthreads();
    for (int off = 256; off > 0; off >>= 1) {
        if (h < off) red[h] += red[h + off];
        __syncthreads();
    }
    if (h == 0) vs[HDIM] = red[0];
}

// ---------------------------------------------------------------------------
// scores[m] = vbsum + sum_h tanh( sum_k A[m,k]W1[h,k] + hb[b,h] ) * vs[h]
// v8: A-IN-REGISTERS (loaded fp32 straight from inputs, cvt in-register to
// fp16 once), W-SLICE-STREAMING. block = 4 waves x 32 m-rows (BM=128,
// grid 1024). Per wave: 32 rows x K=512 of A fp16 in 128 VGPRs. Loop over
// 8 n-slices of W (64 rows x 512 k = 64 KB LDS via GLL, XOR-granule
// swizzle): per slice 128 MFMA/wave + fused tanh*vs epilogue. No
// cross-wave reduction. LDS 66 KB -> 2 blocks/CU.
// ---------------------------------------------------------------------------
__global__ __launch_bounds__(256, 2) void score_mfma(
    const float* __restrict__ Ain,  const ushort* __restrict__ Whi,
    const float* __restrict__ hbp,  const float* __restrict__ vsp,
    float* __restrict__ scores)
{
    __shared__ ushort Ws[64 * 512];          // 64 KB: one W n-slice, full K
    __shared__ float  hb_s[HDIM], vs_s[HDIM + 1];

    const int t    = threadIdx.x;
    const int wid  = t >> 6;        // 0..3
    const int lane = t & 63;
    const int l15  = lane & 15;
    const int l4   = lane >> 4;     // 0..3
    const int m0   = blockIdx.x * 128;
    const int b    = m0 >> 12;      // m0 / 4096

    for (int i = t; i < HDIM; i += 256) { hb_s[i] = hbp[b * HDIM + i]; vs_s[i] = vsp[i]; }
    if (t == 0) vs_s[HDIM] = vsp[HDIM];

    // ---- A: 32 rows x K=512 per wave, fp32 from global, cvt to fp16 regs.
    // Lane (l4, l15) covers row (wid*32 + l15 [+16]) elems [l4*8 + ks*32, +8).
    f16x8 a[2][16];
    const float* a32 = Ain + (size_t)(m0 + (wid << 5) + l15) * HDIM + (l4 << 3);
    #pragma unroll
    for (int i = 0; i < 2; ++i)
        #pragma unroll
        for (int ks = 0; ks < 16; ++ks) {
            const float* p = a32 + (size_t)(i << 4) * HDIM + ks * 32;
            float4 lo = *(const float4*)p;
            float4 hi = *(const float4*)(p + 4);
            f16x8 v;
            v[0] = (_Float16)lo.x; v[1] = (_Float16)lo.y;
            v[2] = (_Float16)lo.z; v[3] = (_Float16)lo.w;
            v[4] = (_Float16)hi.x; v[5] = (_Float16)hi.y;
            v[6] = (_Float16)hi.z; v[7] = (_Float16)hi.w;
            a[i][ks] = v;
        }

    float spart[2][4];
    #pragma unroll
    for (int i = 0; i < 2; ++i)
        #pragma unroll
        for (int r = 0; r < 4; ++r) spart[i][r] = 0.f;

    #pragma unroll 1
    for (int s = 0; s < 8; ++s) {
        const int n0 = s << 6;

        __syncthreads();   // previous slice fully consumed
        // stage W slice: 64 rows x 1 KB; one GLL covers one row (64 lanes x 16B).
        // LDS linear; global granule pre-swizzled: lds[row][gl] = glob[row][gl ^ (row&7)]
        #pragma unroll
        for (int q = 0; q < 16; ++q) {
            const int row = (q << 2) + wid;              // 0..63
            const int g   = lane ^ (row & 7);            // swizzled 16B granule
            GLL(Whi + (size_t)(n0 + row) * HDIM + g * 8, &Ws[row * HDIM]);
        }
        __syncthreads();   // staging complete (vmcnt drained before barrier)

        f32x4 acc[2][4];
        #pragma unroll
        for (int i = 0; i < 2; ++i)
            #pragma unroll
            for (int j = 0; j < 4; ++j) {
                f32x4 z = {0.f, 0.f, 0.f, 0.f};
                acc[i][j] = z;
            }

        #pragma unroll
        for (int ks = 0; ks < 16; ++ks) {
            f16x8 wh[4];
            #pragma unroll
            for (int j = 0; j < 4; ++j) {
                const int rb = (j << 4) + l15;                   // W row in slice
                const int g  = ((ks << 2) + l4) ^ (rb & 7);      // swizzled granule
                wh[j] = *(const f16x8*)&Ws[rb * HDIM + g * 8];
            }
            #pragma unroll
            for (int i = 0; i < 2; ++i)
                #pragma unroll
                for (int j = 0; j < 4; ++j)
                    acc[i][j] = __builtin_amdgcn_mfma_f32_16x16x32_f16(a[i][ks], wh[j], acc[i][j], 0, 0, 0);
        }

        // fused epilogue for this n-slice: tanh + weighted reduce
        #pragma unroll
        for (int j = 0; j < 4; ++j) {
            const int h   = n0 + (j << 4) + l15;
            const float hbv = hb_s[h];
            const float vsv = vs_s[h];
            #pragma unroll
            for (int i = 0; i < 2; ++i)
                #pragma unroll
                for (int r = 0; r < 4; ++r) {
                    float x  = acc[i][j][r] + hbv;
                    float e  = __expf(2.0f * x);
                    float th = 1.0f - __fdividef(2.0f, e + 1.0f);
                    spart[i][r] = fmaf(th, vsv, spart[i][r]);
                }
        }
    }

    // reduce over the 16 column-lanes; rows live in (l4, r)
    #pragma unroll
    for (int i = 0; i < 2; ++i)
        #pragma unroll
        for (int r = 0; r < 4; ++r) {
            float v = spart[i][r];
            v += __shfl_xor(v, 1);
            v += __shfl_xor(v, 2);
            v += __shfl_xor(v, 4);
            v += __shfl_xor(v, 8);
            spart[i][r] = v;
        }

    if (l15 == 0) {
        const float vb = vs_s[HDIM];
        #pragma unroll
        for (int i = 0; i < 2; ++i)
            #pragma unroll
            for (int r = 0; r < 4; ++r)
                scores[m0 + (wid << 5) + (i << 4) + (l4 << 2) + r] = spart[i][r] + vb;
    }
}

// ---------------------------------------------------------------------------
// per-b softmax over s (S=4096)
// ---------------------------------------------------------------------------
__global__ __launch_bounds__(256) void softmax_kernel(
    const float* __restrict__ scores, float* __restrict__ attn)
{
    const int b = blockIdx.x;
    const float* s = scores + (size_t)b * SDIM;
    __shared__ float red[256];
    const int t = threadIdx.x;

    float mx = -INFINITY;
    for (int i = t; i < SDIM; i += 256) mx = fmaxf(mx, s[i]);
    red[t] = mx; __syncthreads();
    for (int off = 128; off > 0; off >>= 1) {
        if (t < off) red[t] = fmaxf(red[t], red[t + off]);
        __syncthreads();
    }
    mx = red[0]; __syncthreads();

    float sum = 0.f;
    for (int i = t; i < SDIM; i += 256) sum += expf(s[i] - mx);
    red[t] = sum; __syncthreads();
    for (int off = 128; off > 0; off >>= 1) {
        if (t < off) red[t] += red[t + off];
        __syncthreads();
    }
    const float inv = 1.0f / red[0];

    for (int i = t; i < SDIM; i += 256)
        attn[(size_t)b * SDIM + i] = expf(s[i] - mx) * inv;
}

// ---------------------------------------------------------------------------
// res[m,:] = attn[m] * inputs[m,:]
// ---------------------------------------------------------------------------
__global__ __launch_bounds__(256) void res_kernel(
    const float* __restrict__ A, const float* __restrict__ attn, float* __restrict__ out)
{
    const size_t total = (size_t)MDIM * HDIM / 4;
    size_t idx = (size_t)blockIdx.x * blockDim.x + threadIdx.x;
    const size_t stride = (size_t)gridDim.x * blockDim.x;
    for (; idx < total; idx += stride) {
        const size_t row = idx / (HDIM / 4);
        const float a = attn[row];
        float4 v = reinterpret_cast<const float4*>(A)[idx];
        v.x *= a; v.y *= a; v.z *= a; v.w *= a;
        reinterpret_cast<float4*>(out)[idx] = v;
    }
}

// ---------------------------------------------------------------------------
extern "C" void kernel_launch(void* const* d_in, const int* in_sizes, int n_in,
                              void* d_out, int out_size, void* d_ws, size_t ws_size,
                              hipStream_t stream)
{
    const float* inputs = (const float*)d_in[0];
    const float* hidden = (const float*)d_in[1];
    const float* Ww     = (const float*)d_in[2];
    const float* Wb     = (const float*)d_in[3];
    const float* Vw     = (const float*)d_in[4];
    const float* Vb     = (const float*)d_in[5];

    float* out      = (float*)d_out;
    float* attn_out = out + (size_t)MDIM * HDIM;        // (B,S,1)

    ushort* Whi    = (ushort*)d_ws;                        // 512 KB
    float*  scores = (float*)(Whi + (size_t)HDIM * HDIM);  // 512 KB
    float*  hb     = scores + MDIM;                        // 64 KB
    float*  vs     = hb + BDIM * HDIM;                     // ~2 KB
    float*  part   = vs + HDIM + 1;                        // 32 KB

    convert_w<<<128, 256, 0, stream>>>(Ww, Whi);
    hb_kernel<<<BDIM, 256, 0, stream>>>(hidden, Ww, Wb, hb);
    vsum_part<<<16, 256, 0, stream>>>(Vw, part);
    vsum_fin<<<1, 512, 0, stream>>>(part, Vb, vs);
    score_mfma<<<MDIM / 128, 256, 0, stream>>>(inputs, Whi, hb, vs, scores);
    softmax_kernel<<<BDIM, 256, 0, stream>>>(scores, attn_out);
    res_kernel<<<2048, 256, 0, stream>>>(inputs, attn_out, out);
}